// Round 2
// baseline (658.387 us; speedup 1.0000x reference)
//
#include <hip/hip_runtime.h>
#include <hip/hip_bf16.h>
#include <math.h>

// Problem constants
#define BB 4
#define SS 256
#define EE 512
#define HH 8
#define HD 64
#define FFD 2048
#define LL 4
#define VV 32000
#define BS (BB*SS)          // 1024 tokens
#define SQRT_E 22.627416997969522f
#define ATTN_SCALE 0.125f   // 1/sqrt(64)

typedef __bf16 bf16;
typedef __attribute__((ext_vector_type(4))) __bf16 bf16x4;
typedef __attribute__((ext_vector_type(8))) __bf16 bf16x8;
typedef __attribute__((ext_vector_type(4))) float f32x4;

#define GLOBAL_AS __attribute__((address_space(1)))
#define LDS_AS    __attribute__((address_space(3)))

__device__ __forceinline__ void load_lds16(const bf16* g, bf16* l) {
    __builtin_amdgcn_global_load_lds((const GLOBAL_AS unsigned int*)g,
                                     (LDS_AS unsigned int*)l, 16, 0, 0);
}

// ---------------- fused fp32->bf16 conversion + embedding/LN head ----------------
// segments (1024 elems / block): inW 3072 | outW 1024 | w1 4096 | w2 4096 | dec 16000 |
// rel 256 | embed_ln 1024 rows
__global__ void cvt_all(const float* __restrict__ inW, const float* __restrict__ outW,
                        const float* __restrict__ w1, const float* __restrict__ w2,
                        const float* __restrict__ dec, const float* __restrict__ rel,
                        bf16* __restrict__ inWb, bf16* __restrict__ outWb,
                        bf16* __restrict__ w1b, bf16* __restrict__ w2b,
                        bf16* __restrict__ decb, bf16* __restrict__ relb,
                        const int* __restrict__ src, const float* __restrict__ emb,
                        const float* __restrict__ nsc, const float* __restrict__ nbi,
                        float* __restrict__ xout) {
    int b = blockIdx.x;
    int t = threadIdx.x;
    if (b >= 28544) {   // ---- embedding gather * sqrt(E) + LayerNorm ----
        int row = b - 28544;
        const float* r = emb + (size_t)src[row] * EE;
        float v0 = r[t] * SQRT_E, v1 = r[t + 256] * SQRT_E;
        float sum = v0 + v1, sq = v0 * v0 + v1 * v1;
        #pragma unroll
        for (int off = 32; off; off >>= 1) {
            sum += __shfl_xor(sum, off);
            sq  += __shfl_xor(sq, off);
        }
        __shared__ float ssum[4], ssq[4];
        int wid = t >> 6, lane = t & 63;
        if (lane == 0) { ssum[wid] = sum; ssq[wid] = sq; }
        __syncthreads();
        sum = ssum[0] + ssum[1] + ssum[2] + ssum[3];
        sq  = ssq[0] + ssq[1] + ssq[2] + ssq[3];
        float mean = sum * (1.0f / EE);
        float var  = sq * (1.0f / EE) - mean * mean;
        float rstd = rsqrtf(var + 1e-5f);
        xout[(size_t)row * EE + t]       = (v0 - mean) * rstd * nsc[t] + nbi[t];
        xout[(size_t)row * EE + t + 256] = (v1 - mean) * rstd * nsc[t + 256] + nbi[t + 256];
        return;
    }
    const float* s; bf16* d; int base; int n;
    if (b < 3072)       { s = inW;  d = inWb;  base = b;         n = 3145728; }
    else if (b < 4096)  { s = outW; d = outWb; base = b - 3072;  n = 1048576; }
    else if (b < 8192)  { s = w1;   d = w1b;   base = b - 4096;  n = 4194304; }
    else if (b < 12288) { s = w2;   d = w2b;   base = b - 8192;  n = 4194304; }
    else if (b < 28288) { s = dec;  d = decb;  base = b - 12288; n = 16384000; }
    else                { s = rel;  d = relb;  base = b - 28288; n = 261632; }
    int i = (base * 256 + t) * 4;
    if (i < n) {
        float4 v = *(const float4*)(s + i);
        bf16x4 o;
        o[0] = (bf16)v.x; o[1] = (bf16)v.y; o[2] = (bf16)v.z; o[3] = (bf16)v.w;
        *(bf16x4*)(d + i) = o;
    }
}

// ---------------- LayerNorm over E=512, one block (256 thr) per row ----------------
template <typename OT>
__global__ void ln_kernel(const float* __restrict__ in, const float* __restrict__ sc,
                          const float* __restrict__ bi, OT* __restrict__ out) {
    int row = blockIdx.x;
    int t = threadIdx.x;
    const float* r = in + (size_t)row * EE;
    float v0 = r[t], v1 = r[t + 256];
    float sum = v0 + v1, sq = v0 * v0 + v1 * v1;
    #pragma unroll
    for (int off = 32; off; off >>= 1) {
        sum += __shfl_xor(sum, off);
        sq  += __shfl_xor(sq, off);
    }
    __shared__ float ssum[4], ssq[4];
    int wid = t >> 6, lane = t & 63;
    if (lane == 0) { ssum[wid] = sum; ssq[wid] = sq; }
    __syncthreads();
    sum = ssum[0] + ssum[1] + ssum[2] + ssum[3];
    sq  = ssq[0] + ssq[1] + ssq[2] + ssq[3];
    float mean = sum * (1.0f / EE);
    float var  = sq * (1.0f / EE) - mean * mean;
    float rstd = rsqrtf(var + 1e-5f);
    out[(size_t)row * EE + t]       = (OT)((v0 - mean) * rstd * sc[t] + bi[t]);
    out[(size_t)row * EE + t + 256] = (OT)((v1 - mean) * rstd * sc[t + 256] + bi[t + 256]);
}

// ---------------- Embedding gather * sqrt(E) + LayerNorm (fp32 out, fallback) ----------------
__global__ void embed_ln_kernel(const int* __restrict__ src, const float* __restrict__ emb,
                                const float* __restrict__ sc, const float* __restrict__ bi,
                                float* __restrict__ out) {
    int row = blockIdx.x;
    int t = threadIdx.x;
    const float* r = emb + (size_t)src[row] * EE;
    float v0 = r[t] * SQRT_E, v1 = r[t + 256] * SQRT_E;
    float sum = v0 + v1, sq = v0 * v0 + v1 * v1;
    #pragma unroll
    for (int off = 32; off; off >>= 1) {
        sum += __shfl_xor(sum, off);
        sq  += __shfl_xor(sq, off);
    }
    __shared__ float ssum[4], ssq[4];
    int wid = t >> 6, lane = t & 63;
    if (lane == 0) { ssum[wid] = sum; ssq[wid] = sq; }
    __syncthreads();
    sum = ssum[0] + ssum[1] + ssum[2] + ssum[3];
    sq  = ssq[0] + ssq[1] + ssq[2] + ssq[3];
    float mean = sum * (1.0f / EE);
    float var  = sq * (1.0f / EE) - mean * mean;
    float rstd = rsqrtf(var + 1e-5f);
    out[(size_t)row * EE + t]       = (v0 - mean) * rstd * sc[t] + bi[t];
    out[(size_t)row * EE + t + 256] = (v1 - mean) * rstd * sc[t + 256] + bi[t + 256];
}

// ---------------- bf16 MFMA NT GEMM: C[M,N] = A[M,K] @ W[N,K]^T ----------------
// 2-phase double-buffered, XOR-swizzled LDS (source-side pre-swizzle for global_load_lds,
// matching XOR on ds_read -- rule 21), optional fused input-LayerNorm (LNF: A comes from
// fp32 Xf; per-row mean/rstd computed in prologue; A staged via regs with T14 split:
// fp32 loads issue before the MFMA cluster, normalize+ds_write after).
// WRVT: cols >= 1024 are V -> write transposed vT[(b*8+h)*64+n][tok].
// SWZ : XCD-cluster swizzle so blocks sharing one W panel land on one XCD.
template <int BM, int BN, int BK, int MODE, int OBF16, int WRVT, int SWZ, int LNF>
__global__ __launch_bounds__(256) void gemm_bf16(
        const bf16* __restrict__ A, const float* __restrict__ Xf,
        const float* __restrict__ lnsc, const float* __restrict__ lnbi,
        const bf16* __restrict__ W, const float* __restrict__ bias,
        void* __restrict__ Cout, const float* __restrict__ res,
        bf16* __restrict__ vT, int M, int N, int K) {
    constexpr int FM = BM / 32, FN = BN / 32;
    constexpr int KSTEPS = BK / 32;
    constexpr int SLOTS = BK / 8;       // 16B chunks per row
    constexpr int SWZM = SLOTS - 1;
    constexpr int NA = BM * BK / 2048;  // staging iters (256 thr x 16B)
    constexpr int NB = BN * BK / 2048;
    __shared__ __align__(16) bf16 Atile[2][BM * BK];
    __shared__ __align__(16) bf16 Btile[2][BN * BK];
    __shared__ float lnm[LNF ? BM : 1], lnr[LNF ? BM : 1];
    int tid = threadIdx.x;
    int wid = tid >> 6, lane = tid & 63;
    int wm = (wid >> 1) * (BM / 2), wn = (wid & 1) * (BN / 2);
    int mrow = lane & 15, quad = lane >> 4;
    int bm, bn;
    if (SWZ) {
        int nbm = gridDim.x;
        int linear = blockIdx.y * nbm + blockIdx.x;
        int total = nbm * gridDim.y;
        int chunk = total >> 3;                 // blocks per XCD (total % 8 == 0)
        int xcd = linear & 7, idx = linear >> 3;
        int g = xcd * chunk + idx;
        bm = (g % nbm) * BM;
        bn = (g / nbm) * BN;
    } else {
        bm = blockIdx.x * BM;
        bn = blockIdx.y * BN;
    }

    if (LNF) {   // per-row LN stats for this block's A rows (x is L2-resident)
        constexpr int TPR = 256 / BM;
        constexpr int CPT = EE / TPR;
        int row = tid / TPR, sub = tid % TPR;
        const float* xr = Xf + (size_t)(bm + row) * EE + sub * CPT;
        float sum = 0.f, sq = 0.f;
        #pragma unroll
        for (int j = 0; j < CPT; j += 4) {
            float4 v = *(const float4*)(xr + j);
            sum += v.x + v.y + v.z + v.w;
            sq  += v.x * v.x + v.y * v.y + v.z * v.z + v.w * v.w;
        }
        #pragma unroll
        for (int d = 1; d < TPR; d <<= 1) { sum += __shfl_xor(sum, d); sq += __shfl_xor(sq, d); }
        if (sub == 0) {
            float mean = sum * (1.0f / EE);
            float var  = sq * (1.0f / EE) - mean * mean;
            lnm[row] = mean; lnr[row] = rsqrtf(var + 1e-5f);
        }
        __syncthreads();
    }

    f32x4 acc[FM][FN];
    #pragma unroll
    for (int i = 0; i < FM; i++)
        #pragma unroll
        for (int j = 0; j < FN; j++)
            acc[i][j] = (f32x4){0.f, 0.f, 0.f, 0.f};

    float4 apre[NA][2];
    auto aload = [&](int k0) {                  // LNF: fp32 A -> regs (issue early)
        #pragma unroll
        for (int s = 0; s < NA; s++) {
            int c = s * 256 + tid; int row = c / SLOTS; int slot = c % SLOTS;
            int kc = (slot ^ (row & SWZM)) * 8;
            const float* p = Xf + (size_t)(bm + row) * K + k0 + kc;
            apre[s][0] = *(const float4*)p;
            apre[s][1] = *(const float4*)(p + 4);
        }
    };
    auto astore = [&](int buf, int k0) {        // LNF: normalize + ds_write (late)
        #pragma unroll
        for (int s = 0; s < NA; s++) {
            int c = s * 256 + tid; int row = c / SLOTS; int slot = c % SLOTS;
            int kc = (slot ^ (row & SWZM)) * 8;
            float mean = lnm[row], rstd = lnr[row];
            float4 s0 = *(const float4*)(lnsc + k0 + kc);
            float4 s1 = *(const float4*)(lnsc + k0 + kc + 4);
            float4 b0 = *(const float4*)(lnbi + k0 + kc);
            float4 b1 = *(const float4*)(lnbi + k0 + kc + 4);
            bf16x8 o;
            o[0] = (bf16)((apre[s][0].x - mean) * rstd * s0.x + b0.x);
            o[1] = (bf16)((apre[s][0].y - mean) * rstd * s0.y + b0.y);
            o[2] = (bf16)((apre[s][0].z - mean) * rstd * s0.z + b0.z);
            o[3] = (bf16)((apre[s][0].w - mean) * rstd * s0.w + b0.w);
            o[4] = (bf16)((apre[s][1].x - mean) * rstd * s1.x + b1.x);
            o[5] = (bf16)((apre[s][1].y - mean) * rstd * s1.y + b1.y);
            o[6] = (bf16)((apre[s][1].z - mean) * rstd * s1.z + b1.z);
            o[7] = (bf16)((apre[s][1].w - mean) * rstd * s1.w + b1.w);
            *(bf16x8*)(&Atile[buf][c * 8]) = o;
        }
    };
    auto stageA = [&](int buf, int k0) {        // bf16 A via async global->LDS
        #pragma unroll
        for (int s = 0; s < NA; s++) {
            int c = s * 256 + tid; int row = c / SLOTS; int slot = c % SLOTS;
            int kc = (slot ^ (row & SWZM)) * 8;
            load_lds16(A + (size_t)(bm + row) * K + k0 + kc, &Atile[buf][c * 8]);
        }
    };
    auto stageB = [&](int buf, int k0) {
        #pragma unroll
        for (int s = 0; s < NB; s++) {
            int c = s * 256 + tid; int row = c / SLOTS; int slot = c % SLOTS;
            int kc = (slot ^ (row & SWZM)) * 8;
            load_lds16(W + (size_t)(bn + row) * K + k0 + kc, &Btile[buf][c * 8]);
        }
    };

    if (LNF) { aload(0); astore(0, 0); } else stageA(0, 0);
    stageB(0, 0);
    __syncthreads();                            // tile 0 ready
    int cur = 0;
    for (int k0 = 0; k0 < K; k0 += BK) {
        bool next = (k0 + BK < K);
        if (next) {
            if (LNF) aload(k0 + BK); else stageA(cur ^ 1, k0 + BK);
            stageB(cur ^ 1, k0 + BK);
        }
        bf16x8 af[FM][KSTEPS], bfv[FN][KSTEPS];
        #pragma unroll
        for (int i = 0; i < FM; i++)
            #pragma unroll
            for (int ks = 0; ks < KSTEPS; ks++) {
                int row = wm + i * 16 + mrow;
                int slot = ks * 4 + quad;
                af[i][ks] = *(const bf16x8*)(&Atile[cur][row * BK + ((slot ^ (row & SWZM)) * 8)]);
            }
        #pragma unroll
        for (int j = 0; j < FN; j++)
            #pragma unroll
            for (int ks = 0; ks < KSTEPS; ks++) {
                int row = wn + j * 16 + mrow;
                int slot = ks * 4 + quad;
                bfv[j][ks] = *(const bf16x8*)(&Btile[cur][row * BK + ((slot ^ (row & SWZM)) * 8)]);
            }
        #pragma unroll
        for (int ks = 0; ks < KSTEPS; ks++)
            #pragma unroll
            for (int i = 0; i < FM; i++)
                #pragma unroll
                for (int j = 0; j < FN; j++)
                    acc[i][j] = __builtin_amdgcn_mfma_f32_16x16x32_bf16(af[i][ks], bfv[j][ks], acc[i][j], 0, 0, 0);
        if (LNF && next) astore(cur ^ 1, k0 + BK);   // T14: write-late, after MFMA cluster
        __syncthreads();
        cur ^= 1;
    }

    #pragma unroll
    for (int i = 0; i < FM; i++) {
        int row0 = bm + wm + i * 16 + quad * 4;
        #pragma unroll
        for (int j = 0; j < FN; j++) {
            int col = bn + wn + j * 16 + mrow;
            float bv = bias[col];
            #pragma unroll
            for (int r = 0; r < 4; r++) {
                int row = row0 + r;
                float v = acc[i][j][r] + bv;
                if (MODE == 1) v = 0.5f * v * (1.0f + erff(v * 0.7071067811865476f));
                if (MODE == 2) v += res[(size_t)row * N + col];
                if (WRVT && col >= 1024) {
                    int cc = col - 1024;
                    vT[(size_t)(((row >> 8) * 8 + (cc >> 6)) * 64 + (cc & 63)) * 256 + (row & 255)] = (bf16)v;
                } else if (OBF16) ((bf16*)Cout)[(size_t)row * N + col] = (bf16)v;
                else              ((float*)Cout)[(size_t)row * N + col] = v;
            }
        }
    }
}

// ---------------- Fused MFMA attention (register-prefetch pipelined) ----------------
__global__ __launch_bounds__(256) void attn_mfma(const bf16* __restrict__ qkv,
        const bf16* __restrict__ relb, const bf16* __restrict__ vT,
        bf16* __restrict__ o) {
    int blk = blockIdx.x;
    int qt = blk & 3, bh = blk >> 2;
    int h = bh & 7, b = bh >> 3;
    int q0 = qt * 64, j0 = 192 - q0;
    int tid = threadIdx.x;
    int wid = tid >> 6, lane = tid & 63;
    int l15 = lane & 15, quad = lane >> 4;
    int mr0 = wid * 16;

    __shared__ __align__(16) bf16 Qs[64 * 72];
    __shared__ __align__(16) bf16 Stg[64 * 72];
    __shared__ __align__(16) bf16 BP[64 * 264];   // bias (stride 256) then P (stride 264)

    int c0 = tid, c1 = 256 + tid;
    int r0 = c0 >> 3, ch0 = (c0 & 7) * 8;
    int r1 = c1 >> 3, ch1 = (c1 & 7) * 8;

    const size_t qbase = (size_t)(b * 256 + q0) * 1536 + h * 64;
    *(bf16x8*)(Qs + r0 * 72 + ch0) = *(const bf16x8*)(qkv + qbase + (size_t)r0 * 1536 + ch0);
    *(bf16x8*)(Qs + r1 * 72 + ch1) = *(const bf16x8*)(qkv + qbase + (size_t)r1 * 1536 + ch1);

    bf16x8 pf0, pf1;
    {
        const size_t rb = (size_t)j0 * 512 + h * 64;
        pf0 = *(const bf16x8*)(relb + rb + (size_t)r0 * 512 + ch0);
        pf1 = *(const bf16x8*)(relb + rb + (size_t)r1 * 512 + ch1);
    }

    __syncthreads();
    bf16x8 af0 = *(const bf16x8*)(Qs + (mr0 + l15) * 72 + quad * 8);
    bf16x8 af1 = *(const bf16x8*)(Qs + (mr0 + l15) * 72 + 32 + quad * 8);

    f32x4 S[16];
    #pragma unroll
    for (int i = 0; i < 16; i++) S[i] = (f32x4){0.f, 0.f, 0.f, 0.f};

    for (int jc = 0; jc < 5; jc++) {
        *(bf16x8*)(Stg + r0 * 72 + ch0) = pf0;
        *(bf16x8*)(Stg + r1 * 72 + ch1) = pf1;
        __syncthreads();
        if (jc < 4) {
            const size_t rb = (size_t)(j0 + (jc + 1) * 64) * 512 + h * 64;
            pf0 = *(const bf16x8*)(relb + rb + (size_t)r0 * 512 + ch0);
            pf1 = *(const bf16x8*)(relb + rb + (size_t)r1 * 512 + ch1);
        } else {
            const size_t kb = (size_t)(b * 256) * 1536 + 512 + h * 64;
            pf0 = *(const bf16x8*)(qkv + kb + (size_t)r0 * 1536 + ch0);
            pf1 = *(const bf16x8*)(qkv + kb + (size_t)r1 * 1536 + ch1);
        }
        #pragma unroll
        for (int jt = 0; jt < 4; jt++) {
            f32x4 acc = (f32x4){0.f, 0.f, 0.f, 0.f};
            bf16x8 bv0 = *(const bf16x8*)(Stg + (jt * 16 + l15) * 72 + quad * 8);
            bf16x8 bv1 = *(const bf16x8*)(Stg + (jt * 16 + l15) * 72 + 32 + quad * 8);
            acc = __builtin_amdgcn_mfma_f32_16x16x32_bf16(af0, bv0, acc, 0, 0, 0);
            acc = __builtin_amdgcn_mfma_f32_16x16x32_bf16(af1, bv1, acc, 0, 0, 0);
            int jp = jc * 64 + jt * 16 + l15;
            #pragma unroll
            for (int r = 0; r < 4; r++) {
                int ll = mr0 + quad * 4 + r;
                int m = jp + ll - 63;
                if (m >= 0 && m < 256) BP[ll * 256 + m] = (bf16)acc[r];
            }
        }
        __syncthreads();
    }

    for (int kc = 0; kc < 4; kc++) {
        *(bf16x8*)(Stg + r0 * 72 + ch0) = pf0;
        *(bf16x8*)(Stg + r1 * 72 + ch1) = pf1;
        __syncthreads();
        if (kc < 3) {
            const size_t kb = (size_t)(b * 256 + (kc + 1) * 64) * 1536 + 512 + h * 64;
            pf0 = *(const bf16x8*)(qkv + kb + (size_t)r0 * 1536 + ch0);
            pf1 = *(const bf16x8*)(qkv + kb + (size_t)r1 * 1536 + ch1);
        } else {
            const size_t vb = (size_t)(bh * 64) * 256;
            pf0 = *(const bf16x8*)(vT + vb + (size_t)r0 * 256 + ch0);
            pf1 = *(const bf16x8*)(vT + vb + (size_t)r1 * 256 + ch1);
        }
        #pragma unroll
        for (int nt = 0; nt < 4; nt++) {
            bf16x8 bv0 = *(const bf16x8*)(Stg + (nt * 16 + l15) * 72 + quad * 8);
            bf16x8 bv1 = *(const bf16x8*)(Stg + (nt * 16 + l15) * 72 + 32 + quad * 8);
            S[kc * 4 + nt] = __builtin_amdgcn_mfma_f32_16x16x32_bf16(af0, bv0, S[kc * 4 + nt], 0, 0, 0);
            S[kc * 4 + nt] = __builtin_amdgcn_mfma_f32_16x16x32_bf16(af1, bv1, S[kc * 4 + nt], 0, 0, 0);
        }
        __syncthreads();
    }

    float rmax[4] = {-1e30f, -1e30f, -1e30f, -1e30f};
    #pragma unroll
    for (int T = 0; T < 16; T++) {
        int m = T * 16 + l15;
        #pragma unroll
        for (int r = 0; r < 4; r++) {
            int ll = mr0 + quad * 4 + r;
            float v = S[T][r] * ATTN_SCALE + (float)BP[ll * 256 + m]
                      + ((m > q0 + ll) ? 1.0f : 0.0f);
            S[T][r] = v;
            rmax[r] = fmaxf(rmax[r], v);
        }
    }
    #pragma unroll
    for (int r = 0; r < 4; r++)
        #pragma unroll
        for (int d = 1; d < 16; d <<= 1)
            rmax[r] = fmaxf(rmax[r], __shfl_xor(rmax[r], d));
    float rsum[4] = {0.f, 0.f, 0.f, 0.f};
    #pragma unroll
    for (int T = 0; T < 16; T++)
        #pragma unroll
        for (int r = 0; r < 4; r++) {
            float p = expf(S[T][r] - rmax[r]);
            S[T][r] = p;
            rsum[r] += p;
        }
    #pragma unroll
    for (int r = 0; r < 4; r++)
        #pragma unroll
        for (int d = 1; d < 16; d <<= 1)
            rsum[r] += __shfl_xor(rsum[r], d);

    __syncthreads();
    #pragma unroll
    for (int T = 0; T < 16; T++)
        #pragma unroll
        for (int r = 0; r < 4; r++)
            BP[(mr0 + quad * 4 + r) * 264 + T * 16 + l15] = (bf16)S[T][r];

    f32x4 oacc[4];
    #pragma unroll
    for (int i = 0; i < 4; i++) oacc[i] = (f32x4){0.f, 0.f, 0.f, 0.f};
    for (int kc = 0; kc < 4; kc++) {
        *(bf16x8*)(Stg + r0 * 72 + ch0) = pf0;
        *(bf16x8*)(Stg + r1 * 72 + ch1) = pf1;
        __syncthreads();
        if (kc < 3) {
            const size_t vb = (size_t)(bh * 64) * 256 + (kc + 1) * 64;
            pf0 = *(const bf16x8*)(vT + vb + (size_t)r0 * 256 + ch0);
            pf1 = *(const bf16x8*)(vT + vb + (size_t)r1 * 256 + ch1);
        }
        #pragma unroll
        for (int ks = 0; ks < 2; ks++) {
            bf16x8 ap = *(const bf16x8*)(BP + (mr0 + l15) * 264 + kc * 64 + ks * 32 + quad * 8);
            #pragma unroll
            for (int nt = 0; nt < 4; nt++) {
                bf16x8 bv = *(const bf16x8*)(Stg + (nt * 16 + l15) * 72 + ks * 32 + quad * 8);
                oacc[nt] = __builtin_amdgcn_mfma_f32_16x16x32_bf16(ap, bv, oacc[nt], 0, 0, 0);
            }
        }
        __syncthreads();
    }

    #pragma unroll
    for (int nt = 0; nt < 4; nt++)
        #pragma unroll
        for (int r = 0; r < 4; r++) {
            int ll = mr0 + quad * 4 + r;
            o[(size_t)(b * 256 + q0 + ll) * 512 + h * 64 + nt * 16 + l15] =
                (bf16)(oacc[nt][r] * (1.0f / rsum[r]));
        }
}

// ---------------- fp32 fallback GEMM + attention (small-ws path) ----------------
template <int MODE>
__global__ void gemm_nt(const float* __restrict__ A, const float* __restrict__ W,
                        const float* __restrict__ bias, float* __restrict__ C,
                        const float* __restrict__ res, int M, int N, int K) {
    __shared__ float As[64][17];
    __shared__ float Ws[64][17];
    int tid = threadIdx.x;
    int tx = tid & 15, ty = tid >> 4;
    int bm = blockIdx.y * 64, bn = blockIdx.x * 64;
    float acc[4][4] = {};
    for (int k0 = 0; k0 < K; k0 += 16) {
        #pragma unroll
        for (int i = 0; i < 4; i++) {
            int idx = tid + i * 256;
            int r = idx >> 4, c = idx & 15;
            As[r][c] = A[(size_t)(bm + r) * K + k0 + c];
            Ws[r][c] = W[(size_t)(bn + r) * K + k0 + c];
        }
        __syncthreads();
        #pragma unroll
        for (int kk = 0; kk < 16; kk++) {
            float a[4], w[4];
            #pragma unroll
            for (int i = 0; i < 4; i++) a[i] = As[ty * 4 + i][kk];
            #pragma unroll
            for (int j = 0; j < 4; j++) w[j] = Ws[tx * 4 + j][kk];
            #pragma unroll
            for (int i = 0; i < 4; i++)
                #pragma unroll
                for (int j = 0; j < 4; j++)
                    acc[i][j] += a[i] * w[j];
        }
        __syncthreads();
    }
    #pragma unroll
    for (int i = 0; i < 4; i++) {
        int row = bm + ty * 4 + i;
        #pragma unroll
        for (int j = 0; j < 4; j++) {
            int col = bn + tx * 4 + j;
            float v = acc[i][j] + bias[col];
            if (MODE == 1) v = 0.5f * v * (1.0f + erff(v * 0.7071067811865476f));
            if (MODE == 2) v += res[(size_t)row * N + col];
            C[(size_t)row * N + col] = v;
        }
    }
}

__global__ void attn_kernel(const float* __restrict__ qkv, const float* __restrict__ rel_table,
                            float* __restrict__ o) {
    int blk = blockIdx.x;
    int l = blk & (SS - 1);
    int bh = blk >> 8;
    int h = bh & (HH - 1);
    int b = bh >> 3;
    int t = threadIdx.x;
    int wid = t >> 6, lane = t & 63;

    __shared__ float qs[HD];
    __shared__ float attn_s[SS];
    __shared__ float swave[4];
    __shared__ float opart[4][HD];

    const float* qrow = qkv + (size_t)(b * SS + l) * (3 * EE) + h * HD;
    if (t < HD) qs[t] = qrow[t];
    __syncthreads();

    const float* krow   = qkv + (size_t)(b * SS + t) * (3 * EE) + EE + h * HD;
    const float* relrow = rel_table + (size_t)(t - l + SS - 1) * EE + h * HD;
    const float4* k4 = reinterpret_cast<const float4*>(krow);
    const float4* r4 = reinterpret_cast<const float4*>(relrow);
    float s1 = 0.f, s2 = 0.f;
    #pragma unroll
    for (int d4 = 0; d4 < HD / 4; d4++) {
        float4 kv = k4[d4], rv = r4[d4];
        float q0 = qs[4 * d4], q1 = qs[4 * d4 + 1], q2 = qs[4 * d4 + 2], q3 = qs[4 * d4 + 3];
        s1 += q0 * kv.x + q1 * kv.y + q2 * kv.z + q3 * kv.w;
        s2 += q0 * rv.x + q1 * rv.y + q2 * rv.z + q3 * rv.w;
    }
    float val = s1 * ATTN_SCALE + s2 + ((t > l) ? 1.0f : 0.0f);

    float m = val;
    #pragma unroll
    for (int off = 32; off; off >>= 1) m = fmaxf(m, __shfl_xor(m, off));
    if (lane == 0) swave[wid] = m;
    __syncthreads();
    m = fmaxf(fmaxf(swave[0], swave[1]), fmaxf(swave[2], swave[3]));
    float p = expf(val - m);
    float s = p;
    #pragma unroll
    for (int off = 32; off; off >>= 1) s += __shfl_xor(s, off);
    __syncthreads();
    if (lane == 0) swave[wid] = s;
    __syncthreads();
    float tot = swave[0] + swave[1] + swave[2] + swave[3];
    attn_s[t] = p;
    __syncthreads();

    int d = t & 63, part = t >> 6;
    const float* vbase = qkv + (size_t)(b * SS) * (3 * EE) + 2 * EE + h * HD + d;
    float acc = 0.f;
    int m0 = part * 64;
    #pragma unroll 8
    for (int mm = m0; mm < m0 + 64; mm++)
        acc += attn_s[mm] * vbase[(size_t)mm * (3 * EE)];
    opart[part][d] = acc;
    __syncthreads();
    if (t < 64) {
        float ov = (opart[0][d] + opart[1][d] + opart[2][d] + opart[3][d]) / tot;
        o[(size_t)(b * SS + l) * EE + h * HD + d] = ov;
    }
}

extern "C" void kernel_launch(void* const* d_in, const int* in_sizes, int n_in,
                              void* d_out, int out_size, void* d_ws, size_t ws_size,
                              hipStream_t stream) {
    const int*   src    = (const int*)  d_in[0];
    const float* emb    = (const float*)d_in[1];
    const float* rel    = (const float*)d_in[2];
    const float* nin_s  = (const float*)d_in[3];
    const float* nin_b  = (const float*)d_in[4];
    const float* inW    = (const float*)d_in[5];
    const float* inB    = (const float*)d_in[6];
    const float* outW   = (const float*)d_in[7];
    const float* outB   = (const float*)d_in[8];
    const float* ln1_s  = (const float*)d_in[9];
    const float* ln1_b  = (const float*)d_in[10];
    const float* ln2_s  = (const float*)d_in[11];
    const float* ln2_b  = (const float*)d_in[12];
    const float* w1     = (const float*)d_in[13];
    const float* b1     = (const float*)d_in[14];
    const float* w2     = (const float*)d_in[15];
    const float* b2     = (const float*)d_in[16];
    const float* normf_s= (const float*)d_in[17];
    const float* normf_b= (const float*)d_in[18];
    const float* dec_w  = (const float*)d_in[19];
    const float* dec_b  = (const float*)d_in[20];
    float* out = (float*)d_out;   // [1024, 32000]

    const size_t n_inW  = (size_t)LL * 3 * EE * EE;
    const size_t n_outW = (size_t)LL * EE * EE;
    const size_t n_w1   = (size_t)LL * FFD * EE;
    const size_t n_w2   = (size_t)LL * EE * FFD;
    const size_t n_dec  = (size_t)VV * EE;

    float* x    = (float*)d_ws;                       // [BS,EE] fp32 residual
    bf16*  qkvb = (bf16*)(x + (size_t)BS * EE);       // [BS,3EE] bf16
    bf16*  hb   = qkvb + (size_t)BS * 3 * EE;         // [BS,EE]
    bf16*  ob   = hb + (size_t)BS * EE;               // [BS,EE]
    bf16*  ffb  = ob + (size_t)BS * EE;               // [BS,FFD]
    bf16*  vTb  = ffb + (size_t)BS * FFD;             // [32][64][256]
    bf16*  relb = vTb + (size_t)BS * 512;             // [512][512] (row 511 unused)
    bf16*  inWb  = relb + (size_t)512 * EE;
    bf16*  outWb = inWb + n_inW;
    bf16*  w1b   = outWb + n_outW;
    bf16*  w2b   = w1b + n_w1;
    bf16*  decWb = w2b + n_w2;
    size_t needed = (size_t)((char*)(decWb + n_dec) - (char*)d_ws);

    if (ws_size >= needed) {
        cvt_all<<<29568, 256, 0, stream>>>(inW, outW, w1, w2, dec_w, rel,
                                           inWb, outWb, w1b, w2b, decWb, relb,
                                           src, emb, nin_s, nin_b, x);

        for (int l = 0; l < LL; l++) {
            // QKV projection with fused ln1 (reads fp32 x), writes qkv bf16 + V^T
            gemm_bf16<64, 64, 64, 0, 1, 1, 0, 1><<<dim3(BS / 64, 3 * EE / 64), 256, 0, stream>>>(
                nullptr, x, ln1_s + (size_t)l * EE, ln1_b + (size_t)l * EE,
                inWb + (size_t)l * 3 * EE * EE, inB + (size_t)l * 3 * EE,
                qkvb, nullptr, vTb, BS, 3 * EE, EE);
            attn_mfma<<<BB * HH * 4, 256, 0, stream>>>(qkvb, relb, vTb, ob);
            // out-projection + residual (BM=32 -> 256 blocks, full machine)
            gemm_bf16<32, 64, 64, 2, 0, 0, 0, 0><<<dim3(BS / 32, EE / 64), 256, 0, stream>>>(
                ob, nullptr, nullptr, nullptr,
                outWb + (size_t)l * EE * EE, outB + (size_t)l * EE,
                x, x, nullptr, BS, EE, EE);
            // FF1 with fused ln2 + GELU
            gemm_bf16<64, 64, 64, 1, 1, 0, 0, 1><<<dim3(BS / 64, FFD / 64), 256, 0, stream>>>(
                nullptr, x, ln2_s + (size_t)l * EE, ln2_b + (size_t)l * EE,
                w1b + (size_t)l * FFD * EE, b1 + (size_t)l * FFD,
                ffb, nullptr, nullptr, BS, FFD, EE);
            // FF2 + residual
            gemm_bf16<32, 64, 64, 2, 0, 0, 0, 0><<<dim3(BS / 32, EE / 64), 256, 0, stream>>>(
                ffb, nullptr, nullptr, nullptr,
                w2b + (size_t)l * EE * FFD, b2 + (size_t)l * EE,
                x, x, nullptr, BS, EE, FFD);
        }

        ln_kernel<bf16><<<BS, 256, 0, stream>>>(x, normf_s, normf_b, hb);
        gemm_bf16<128, 128, 32, 0, 0, 0, 1, 0><<<dim3(BS / 128, VV / 128), 256, 0, stream>>>(
            hb, nullptr, nullptr, nullptr, decWb, dec_b, out, nullptr, nullptr, BS, VV, EE);
    } else {
        float* h     = x + (size_t)BS * EE;
        float* qkvf  = h + (size_t)BS * EE;
        float* o     = qkvf + (size_t)BS * 3 * EE;
        float* ffmid = o + (size_t)BS * EE;

        embed_ln_kernel<<<BS, 256, 0, stream>>>(src, emb, nin_s, nin_b, x);
        for (int l = 0; l < LL; l++) {
            ln_kernel<float><<<BS, 256, 0, stream>>>(x, ln1_s + l * EE, ln1_b + l * EE, h);
            gemm_nt<0><<<dim3(3 * EE / 64, BS / 64), 256, 0, stream>>>(
                h, inW + (size_t)l * 3 * EE * EE, inB + (size_t)l * 3 * EE, qkvf, nullptr,
                BS, 3 * EE, EE);
            attn_kernel<<<BB * HH * SS, 256, 0, stream>>>(qkvf, rel, o);
            gemm_nt<2><<<dim3(EE / 64, BS / 64), 256, 0, stream>>>(
                o, outW + (size_t)l * EE * EE, outB + (size_t)l * EE, x, x,
                BS, EE, EE);
            ln_kernel<float><<<BS, 256, 0, stream>>>(x, ln2_s + l * EE, ln2_b + l * EE, h);
            gemm_nt<1><<<dim3(FFD / 64, BS / 64), 256, 0, stream>>>(
                h, w1 + (size_t)l * FFD * EE, b1 + (size_t)l * FFD, ffmid, nullptr,
                BS, FFD, EE);
            gemm_nt<2><<<dim3(EE / 64, BS / 64), 256, 0, stream>>>(
                ffmid, w2 + (size_t)l * EE * FFD, b2 + (size_t)l * EE, x, x,
                BS, EE, FFD);
        }
        ln_kernel<float><<<BS, 256, 0, stream>>>(x, normf_s, normf_b, h);
        gemm_nt<0><<<dim3(VV / 64, BS / 64), 256, 0, stream>>>(
            h, dec_w, dec_b, out, nullptr, BS, VV, EE);
    }
}

// Round 3
// 577.219 us; speedup vs baseline: 1.1406x; 1.1406x over previous
//
#include <hip/hip_runtime.h>
#include <hip/hip_bf16.h>
#include <math.h>

// Problem constants
#define BB 4
#define SS 256
#define EE 512
#define HH 8
#define HD 64
#define FFD 2048
#define LL 4
#define VV 32000
#define BS (BB*SS)          // 1024 tokens
#define SQRT_E 22.627416997969522f
#define ATTN_SCALE 0.125f   // 1/sqrt(64)

typedef __bf16 bf16;
typedef __attribute__((ext_vector_type(4))) __bf16 bf16x4;
typedef __attribute__((ext_vector_type(8))) __bf16 bf16x8;
typedef __attribute__((ext_vector_type(4))) float f32x4;

#define GLOBAL_AS __attribute__((address_space(1)))
#define LDS_AS    __attribute__((address_space(3)))

__device__ __forceinline__ void load_lds16(const bf16* g, bf16* l) {
    __builtin_amdgcn_global_load_lds((const GLOBAL_AS unsigned int*)g,
                                     (LDS_AS unsigned int*)l, 16, 0, 0);
}

// ---------------- fused fp32->bf16 conversion + embedding/LN head ----------------
// segments (1024 elems / block): inW 3072 | outW 1024 | w1 4096 | w2 4096 | dec 16000 |
// rel 256 | embed_ln 1024 rows
__global__ void cvt_all(const float* __restrict__ inW, const float* __restrict__ outW,
                        const float* __restrict__ w1, const float* __restrict__ w2,
                        const float* __restrict__ dec, const float* __restrict__ rel,
                        bf16* __restrict__ inWb, bf16* __restrict__ outWb,
                        bf16* __restrict__ w1b, bf16* __restrict__ w2b,
                        bf16* __restrict__ decb, bf16* __restrict__ relb,
                        const int* __restrict__ src, const float* __restrict__ emb,
                        const float* __restrict__ nsc, const float* __restrict__ nbi,
                        float* __restrict__ xout) {
    int b = blockIdx.x;
    int t = threadIdx.x;
    if (b >= 28544) {   // ---- embedding gather * sqrt(E) + LayerNorm ----
        int row = b - 28544;
        const float* r = emb + (size_t)src[row] * EE;
        float v0 = r[t] * SQRT_E, v1 = r[t + 256] * SQRT_E;
        float sum = v0 + v1, sq = v0 * v0 + v1 * v1;
        #pragma unroll
        for (int off = 32; off; off >>= 1) {
            sum += __shfl_xor(sum, off);
            sq  += __shfl_xor(sq, off);
        }
        __shared__ float ssum[4], ssq[4];
        int wid = t >> 6, lane = t & 63;
        if (lane == 0) { ssum[wid] = sum; ssq[wid] = sq; }
        __syncthreads();
        sum = ssum[0] + ssum[1] + ssum[2] + ssum[3];
        sq  = ssq[0] + ssq[1] + ssq[2] + ssq[3];
        float mean = sum * (1.0f / EE);
        float var  = sq * (1.0f / EE) - mean * mean;
        float rstd = rsqrtf(var + 1e-5f);
        xout[(size_t)row * EE + t]       = (v0 - mean) * rstd * nsc[t] + nbi[t];
        xout[(size_t)row * EE + t + 256] = (v1 - mean) * rstd * nsc[t + 256] + nbi[t + 256];
        return;
    }
    const float* s; bf16* d; int base; int n;
    if (b < 3072)       { s = inW;  d = inWb;  base = b;         n = 3145728; }
    else if (b < 4096)  { s = outW; d = outWb; base = b - 3072;  n = 1048576; }
    else if (b < 8192)  { s = w1;   d = w1b;   base = b - 4096;  n = 4194304; }
    else if (b < 12288) { s = w2;   d = w2b;   base = b - 8192;  n = 4194304; }
    else if (b < 28288) { s = dec;  d = decb;  base = b - 12288; n = 16384000; }
    else                { s = rel;  d = relb;  base = b - 28288; n = 261632; }
    int i = (base * 256 + t) * 4;
    if (i < n) {
        float4 v = *(const float4*)(s + i);
        bf16x4 o;
        o[0] = (bf16)v.x; o[1] = (bf16)v.y; o[2] = (bf16)v.z; o[3] = (bf16)v.w;
        *(bf16x4*)(d + i) = o;
    }
}

// ---------------- LayerNorm over E=512, one block (256 thr) per row ----------------
template <typename OT>
__global__ void ln_kernel(const float* __restrict__ in, const float* __restrict__ sc,
                          const float* __restrict__ bi, OT* __restrict__ out) {
    int row = blockIdx.x;
    int t = threadIdx.x;
    const float* r = in + (size_t)row * EE;
    float v0 = r[t], v1 = r[t + 256];
    float sum = v0 + v1, sq = v0 * v0 + v1 * v1;
    #pragma unroll
    for (int off = 32; off; off >>= 1) {
        sum += __shfl_xor(sum, off);
        sq  += __shfl_xor(sq, off);
    }
    __shared__ float ssum[4], ssq[4];
    int wid = t >> 6, lane = t & 63;
    if (lane == 0) { ssum[wid] = sum; ssq[wid] = sq; }
    __syncthreads();
    sum = ssum[0] + ssum[1] + ssum[2] + ssum[3];
    sq  = ssq[0] + ssq[1] + ssq[2] + ssq[3];
    float mean = sum * (1.0f / EE);
    float var  = sq * (1.0f / EE) - mean * mean;
    float rstd = rsqrtf(var + 1e-5f);
    out[(size_t)row * EE + t]       = (OT)((v0 - mean) * rstd * sc[t] + bi[t]);
    out[(size_t)row * EE + t + 256] = (OT)((v1 - mean) * rstd * sc[t + 256] + bi[t + 256]);
}

// ---------------- Embedding gather * sqrt(E) + LayerNorm (fp32 out, fallback) ----------------
__global__ void embed_ln_kernel(const int* __restrict__ src, const float* __restrict__ emb,
                                const float* __restrict__ sc, const float* __restrict__ bi,
                                float* __restrict__ out) {
    int row = blockIdx.x;
    int t = threadIdx.x;
    const float* r = emb + (size_t)src[row] * EE;
    float v0 = r[t] * SQRT_E, v1 = r[t + 256] * SQRT_E;
    float sum = v0 + v1, sq = v0 * v0 + v1 * v1;
    #pragma unroll
    for (int off = 32; off; off >>= 1) {
        sum += __shfl_xor(sum, off);
        sq  += __shfl_xor(sq, off);
    }
    __shared__ float ssum[4], ssq[4];
    int wid = t >> 6, lane = t & 63;
    if (lane == 0) { ssum[wid] = sum; ssq[wid] = sq; }
    __syncthreads();
    sum = ssum[0] + ssum[1] + ssum[2] + ssum[3];
    sq  = ssq[0] + ssq[1] + ssq[2] + ssq[3];
    float mean = sum * (1.0f / EE);
    float var  = sq * (1.0f / EE) - mean * mean;
    float rstd = rsqrtf(var + 1e-5f);
    out[(size_t)row * EE + t]       = (v0 - mean) * rstd * sc[t] + bi[t];
    out[(size_t)row * EE + t + 256] = (v1 - mean) * rstd * sc[t + 256] + bi[t + 256];
}

// ---------------- bf16 MFMA NT GEMM: C[M,N] = A[M,K] @ W[N,K]^T ----------------
// R1 structure: 2-phase double-buffered global_load_lds staging, BK=32, linear LDS.
// SPLITK>1: grid.z splits K; partials combined via fp32 atomicAdd onto Cout (which
// already holds the residual); kp==0 adds bias. Order-independent => XCD-safe.
// WRVT: cols >= 1024 are V -> write transposed vT[(b*8+h)*64+n][tok].
// SWZ : XCD-cluster swizzle so blocks sharing one W panel land on one XCD.
template <int BM, int BN, int MODE, int OBF16, int WRVT, int SWZ, int SPLITK>
__global__ __launch_bounds__(256) void gemm_bf16(
        const bf16* __restrict__ A, const bf16* __restrict__ W,
        const float* __restrict__ bias, void* __restrict__ Cout,
        const float* __restrict__ res, bf16* __restrict__ vT,
        int M, int N, int K) {
    constexpr int FM = BM / 32, FN = BN / 32;
    __shared__ bf16 Atile[2][BM * 32];
    __shared__ bf16 Btile[2][BN * 32];
    int tid = threadIdx.x;
    int wid = tid >> 6, lane = tid & 63;
    int wm = (wid >> 1) * (BM / 2), wn = (wid & 1) * (BN / 2);
    int bm, bn;
    if (SWZ) {
        int nbm = gridDim.x;
        int linear = blockIdx.y * nbm + blockIdx.x;
        int total = nbm * gridDim.y;
        int chunk = total >> 3;                 // blocks per XCD (total % 8 == 0)
        int xcd = linear & 7, idx = linear >> 3;
        int g = xcd * chunk + idx;
        bm = (g % nbm) * BM;
        bn = (g / nbm) * BN;
    } else {
        bm = blockIdx.x * BM;
        bn = blockIdx.y * BN;
    }
    int kp = (SPLITK > 1) ? blockIdx.z : 0;
    int kbeg = kp * (K / SPLITK);
    int kend = kbeg + K / SPLITK;

    f32x4 acc[FM][FN];
    #pragma unroll
    for (int i = 0; i < FM; i++)
        #pragma unroll
        for (int j = 0; j < FN; j++)
            acc[i][j] = (f32x4){0.f, 0.f, 0.f, 0.f};

    int mrow = lane & 15, kq = (lane >> 4) * 8;

    auto stage = [&](int buf, int k0) {
        #pragma unroll
        for (int it = 0; it < BM / 64; it++) {
            int c = it * 256 + tid;
            int row = c >> 2, kc = (c & 3) * 8;
            load_lds16(A + (size_t)(bm + row) * K + k0 + kc, &Atile[buf][c * 8]);
        }
        #pragma unroll
        for (int it = 0; it < BN / 64; it++) {
            int c = it * 256 + tid;
            int row = c >> 2, kc = (c & 3) * 8;
            load_lds16(W + (size_t)(bn + row) * K + k0 + kc, &Btile[buf][c * 8]);
        }
    };

    stage(0, kbeg);
    __syncthreads();                            // tile 0 ready
    int cur = 0;
    for (int k0 = kbeg; k0 < kend; k0 += 32) {
        if (k0 + 32 < kend) stage(cur ^ 1, k0 + 32);   // prefetch next tile
        bf16x8 af[FM], bfv[FN];
        #pragma unroll
        for (int i = 0; i < FM; i++)
            af[i] = *(const bf16x8*)(&Atile[cur][(wm + i * 16 + mrow) * 32 + kq]);
        #pragma unroll
        for (int j = 0; j < FN; j++)
            bfv[j] = *(const bf16x8*)(&Btile[cur][(wn + j * 16 + mrow) * 32 + kq]);
        #pragma unroll
        for (int i = 0; i < FM; i++)
            #pragma unroll
            for (int j = 0; j < FN; j++)
                acc[i][j] = __builtin_amdgcn_mfma_f32_16x16x32_bf16(af[i], bfv[j], acc[i][j], 0, 0, 0);
        __syncthreads();
        cur ^= 1;
    }

    #pragma unroll
    for (int i = 0; i < FM; i++) {
        int row0 = bm + wm + i * 16 + (lane >> 4) * 4;
        #pragma unroll
        for (int j = 0; j < FN; j++) {
            int col = bn + wn + j * 16 + (lane & 15);
            float bv = bias[col];
            #pragma unroll
            for (int r = 0; r < 4; r++) {
                int row = row0 + r;
                if (SPLITK > 1) {               // MODE==2 style: accumulate onto Cout (fp32)
                    float v = acc[i][j][r];
                    if (kp == 0) v += bv;
                    atomicAdd((float*)Cout + (size_t)row * N + col, v);
                    continue;
                }
                float v = acc[i][j][r] + bv;
                if (MODE == 1) v = 0.5f * v * (1.0f + erff(v * 0.7071067811865476f));
                if (MODE == 2) v += res[(size_t)row * N + col];
                if (WRVT && col >= 1024) {
                    int cc = col - 1024;
                    vT[(size_t)(((row >> 8) * 8 + (cc >> 6)) * 64 + (cc & 63)) * 256 + (row & 255)] = (bf16)v;
                } else if (OBF16) ((bf16*)Cout)[(size_t)row * N + col] = (bf16)v;
                else              ((float*)Cout)[(size_t)row * N + col] = v;
            }
        }
    }
}

// ---------------- Fused MFMA attention (register-prefetch pipelined, R1) ----------------
__global__ __launch_bounds__(256) void attn_mfma(const bf16* __restrict__ qkv,
        const bf16* __restrict__ relb, const bf16* __restrict__ vT,
        bf16* __restrict__ o) {
    int blk = blockIdx.x;
    int qt = blk & 3, bh = blk >> 2;
    int h = bh & 7, b = bh >> 3;
    int q0 = qt * 64, j0 = 192 - q0;
    int tid = threadIdx.x;
    int wid = tid >> 6, lane = tid & 63;
    int l15 = lane & 15, quad = lane >> 4;
    int mr0 = wid * 16;

    __shared__ __align__(16) bf16 Qs[64 * 72];
    __shared__ __align__(16) bf16 Stg[64 * 72];
    __shared__ __align__(16) bf16 BP[64 * 264];   // bias (stride 256) then P (stride 264)

    int c0 = tid, c1 = 256 + tid;
    int r0 = c0 >> 3, ch0 = (c0 & 7) * 8;
    int r1 = c1 >> 3, ch1 = (c1 & 7) * 8;

    const size_t qbase = (size_t)(b * 256 + q0) * 1536 + h * 64;
    *(bf16x8*)(Qs + r0 * 72 + ch0) = *(const bf16x8*)(qkv + qbase + (size_t)r0 * 1536 + ch0);
    *(bf16x8*)(Qs + r1 * 72 + ch1) = *(const bf16x8*)(qkv + qbase + (size_t)r1 * 1536 + ch1);

    bf16x8 pf0, pf1;
    {
        const size_t rb = (size_t)j0 * 512 + h * 64;
        pf0 = *(const bf16x8*)(relb + rb + (size_t)r0 * 512 + ch0);
        pf1 = *(const bf16x8*)(relb + rb + (size_t)r1 * 512 + ch1);
    }

    __syncthreads();
    bf16x8 af0 = *(const bf16x8*)(Qs + (mr0 + l15) * 72 + quad * 8);
    bf16x8 af1 = *(const bf16x8*)(Qs + (mr0 + l15) * 72 + 32 + quad * 8);

    f32x4 S[16];
    #pragma unroll
    for (int i = 0; i < 16; i++) S[i] = (f32x4){0.f, 0.f, 0.f, 0.f};

    for (int jc = 0; jc < 5; jc++) {
        *(bf16x8*)(Stg + r0 * 72 + ch0) = pf0;
        *(bf16x8*)(Stg + r1 * 72 + ch1) = pf1;
        __syncthreads();
        if (jc < 4) {
            const size_t rb = (size_t)(j0 + (jc + 1) * 64) * 512 + h * 64;
            pf0 = *(const bf16x8*)(relb + rb + (size_t)r0 * 512 + ch0);
            pf1 = *(const bf16x8*)(relb + rb + (size_t)r1 * 512 + ch1);
        } else {
            const size_t kb = (size_t)(b * 256) * 1536 + 512 + h * 64;
            pf0 = *(const bf16x8*)(qkv + kb + (size_t)r0 * 1536 + ch0);
            pf1 = *(const bf16x8*)(qkv + kb + (size_t)r1 * 1536 + ch1);
        }
        #pragma unroll
        for (int jt = 0; jt < 4; jt++) {
            f32x4 acc = (f32x4){0.f, 0.f, 0.f, 0.f};
            bf16x8 bv0 = *(const bf16x8*)(Stg + (jt * 16 + l15) * 72 + quad * 8);
            bf16x8 bv1 = *(const bf16x8*)(Stg + (jt * 16 + l15) * 72 + 32 + quad * 8);
            acc = __builtin_amdgcn_mfma_f32_16x16x32_bf16(af0, bv0, acc, 0, 0, 0);
            acc = __builtin_amdgcn_mfma_f32_16x16x32_bf16(af1, bv1, acc, 0, 0, 0);
            int jp = jc * 64 + jt * 16 + l15;
            #pragma unroll
            for (int r = 0; r < 4; r++) {
                int ll = mr0 + quad * 4 + r;
                int m = jp + ll - 63;
                if (m >= 0 && m < 256) BP[ll * 256 + m] = (bf16)acc[r];
            }
        }
        __syncthreads();
    }

    for (int kc = 0; kc < 4; kc++) {
        *(bf16x8*)(Stg + r0 * 72 + ch0) = pf0;
        *(bf16x8*)(Stg + r1 * 72 + ch1) = pf1;
        __syncthreads();
        if (kc < 3) {
            const size_t kb = (size_t)(b * 256 + (kc + 1) * 64) * 1536 + 512 + h * 64;
            pf0 = *(const bf16x8*)(qkv + kb + (size_t)r0 * 1536 + ch0);
            pf1 = *(const bf16x8*)(qkv + kb + (size_t)r1 * 1536 + ch1);
        } else {
            const size_t vb = (size_t)(bh * 64) * 256;
            pf0 = *(const bf16x8*)(vT + vb + (size_t)r0 * 256 + ch0);
            pf1 = *(const bf16x8*)(vT + vb + (size_t)r1 * 256 + ch1);
        }
        #pragma unroll
        for (int nt = 0; nt < 4; nt++) {
            bf16x8 bv0 = *(const bf16x8*)(Stg + (nt * 16 + l15) * 72 + quad * 8);
            bf16x8 bv1 = *(const bf16x8*)(Stg + (nt * 16 + l15) * 72 + 32 + quad * 8);
            S[kc * 4 + nt] = __builtin_amdgcn_mfma_f32_16x16x32_bf16(af0, bv0, S[kc * 4 + nt], 0, 0, 0);
            S[kc * 4 + nt] = __builtin_amdgcn_mfma_f32_16x16x32_bf16(af1, bv1, S[kc * 4 + nt], 0, 0, 0);
        }
        __syncthreads();
    }

    float rmax[4] = {-1e30f, -1e30f, -1e30f, -1e30f};
    #pragma unroll
    for (int T = 0; T < 16; T++) {
        int m = T * 16 + l15;
        #pragma unroll
        for (int r = 0; r < 4; r++) {
            int ll = mr0 + quad * 4 + r;
            float v = S[T][r] * ATTN_SCALE + (float)BP[ll * 256 + m]
                      + ((m > q0 + ll) ? 1.0f : 0.0f);
            S[T][r] = v;
            rmax[r] = fmaxf(rmax[r], v);
        }
    }
    #pragma unroll
    for (int r = 0; r < 4; r++)
        #pragma unroll
        for (int d = 1; d < 16; d <<= 1)
            rmax[r] = fmaxf(rmax[r], __shfl_xor(rmax[r], d));
    float rsum[4] = {0.f, 0.f, 0.f, 0.f};
    #pragma unroll
    for (int T = 0; T < 16; T++)
        #pragma unroll
        for (int r = 0; r < 4; r++) {
            float p = expf(S[T][r] - rmax[r]);
            S[T][r] = p;
            rsum[r] += p;
        }
    #pragma unroll
    for (int r = 0; r < 4; r++)
        #pragma unroll
        for (int d = 1; d < 16; d <<= 1)
            rsum[r] += __shfl_xor(rsum[r], d);

    __syncthreads();
    #pragma unroll
    for (int T = 0; T < 16; T++)
        #pragma unroll
        for (int r = 0; r < 4; r++)
            BP[(mr0 + quad * 4 + r) * 264 + T * 16 + l15] = (bf16)S[T][r];

    f32x4 oacc[4];
    #pragma unroll
    for (int i = 0; i < 4; i++) oacc[i] = (f32x4){0.f, 0.f, 0.f, 0.f};
    for (int kc = 0; kc < 4; kc++) {
        *(bf16x8*)(Stg + r0 * 72 + ch0) = pf0;
        *(bf16x8*)(Stg + r1 * 72 + ch1) = pf1;
        __syncthreads();
        if (kc < 3) {
            const size_t vb = (size_t)(bh * 64) * 256 + (kc + 1) * 64;
            pf0 = *(const bf16x8*)(vT + vb + (size_t)r0 * 256 + ch0);
            pf1 = *(const bf16x8*)(vT + vb + (size_t)r1 * 256 + ch1);
        }
        #pragma unroll
        for (int ks = 0; ks < 2; ks++) {
            bf16x8 ap = *(const bf16x8*)(BP + (mr0 + l15) * 264 + kc * 64 + ks * 32 + quad * 8);
            #pragma unroll
            for (int nt = 0; nt < 4; nt++) {
                bf16x8 bv = *(const bf16x8*)(Stg + (nt * 16 + l15) * 72 + ks * 32 + quad * 8);
                oacc[nt] = __builtin_amdgcn_mfma_f32_16x16x32_bf16(ap, bv, oacc[nt], 0, 0, 0);
            }
        }
        __syncthreads();
    }

    #pragma unroll
    for (int nt = 0; nt < 4; nt++)
        #pragma unroll
        for (int r = 0; r < 4; r++) {
            int ll = mr0 + quad * 4 + r;
            o[(size_t)(b * 256 + q0 + ll) * 512 + h * 64 + nt * 16 + l15] =
                (bf16)(oacc[nt][r] * (1.0f / rsum[r]));
        }
}

// ---------------- fp32 fallback GEMM + attention (small-ws path) ----------------
template <int MODE>
__global__ void gemm_nt(const float* __restrict__ A, const float* __restrict__ W,
                        const float* __restrict__ bias, float* __restrict__ C,
                        const float* __restrict__ res, int M, int N, int K) {
    __shared__ float As[64][17];
    __shared__ float Ws[64][17];
    int tid = threadIdx.x;
    int tx = tid & 15, ty = tid >> 4;
    int bm = blockIdx.y * 64, bn = blockIdx.x * 64;
    float acc[4][4] = {};
    for (int k0 = 0; k0 < K; k0 += 16) {
        #pragma unroll
        for (int i = 0; i < 4; i++) {
            int idx = tid + i * 256;
            int r = idx >> 4, c = idx & 15;
            As[r][c] = A[(size_t)(bm + r) * K + k0 + c];
            Ws[r][c] = W[(size_t)(bn + r) * K + k0 + c];
        }
        __syncthreads();
        #pragma unroll
        for (int kk = 0; kk < 16; kk++) {
            float a[4], w[4];
            #pragma unroll
            for (int i = 0; i < 4; i++) a[i] = As[ty * 4 + i][kk];
            #pragma unroll
            for (int j = 0; j < 4; j++) w[j] = Ws[tx * 4 + j][kk];
            #pragma unroll
            for (int i = 0; i < 4; i++)
                #pragma unroll
                for (int j = 0; j < 4; j++)
                    acc[i][j] += a[i] * w[j];
        }
        __syncthreads();
    }
    #pragma unroll
    for (int i = 0; i < 4; i++) {
        int row = bm + ty * 4 + i;
        #pragma unroll
        for (int j = 0; j < 4; j++) {
            int col = bn + tx * 4 + j;
            float v = acc[i][j] + bias[col];
            if (MODE == 1) v = 0.5f * v * (1.0f + erff(v * 0.7071067811865476f));
            if (MODE == 2) v += res[(size_t)row * N + col];
            C[(size_t)row * N + col] = v;
        }
    }
}

__global__ void attn_kernel(const float* __restrict__ qkv, const float* __restrict__ rel_table,
                            float* __restrict__ o) {
    int blk = blockIdx.x;
    int l = blk & (SS - 1);
    int bh = blk >> 8;
    int h = bh & (HH - 1);
    int b = bh >> 3;
    int t = threadIdx.x;
    int wid = t >> 6, lane = t & 63;

    __shared__ float qs[HD];
    __shared__ float attn_s[SS];
    __shared__ float swave[4];
    __shared__ float opart[4][HD];

    const float* qrow = qkv + (size_t)(b * SS + l) * (3 * EE) + h * HD;
    if (t < HD) qs[t] = qrow[t];
    __syncthreads();

    const float* krow   = qkv + (size_t)(b * SS + t) * (3 * EE) + EE + h * HD;
    const float* relrow = rel_table + (size_t)(t - l + SS - 1) * EE + h * HD;
    const float4* k4 = reinterpret_cast<const float4*>(krow);
    const float4* r4 = reinterpret_cast<const float4*>(relrow);
    float s1 = 0.f, s2 = 0.f;
    #pragma unroll
    for (int d4 = 0; d4 < HD / 4; d4++) {
        float4 kv = k4[d4], rv = r4[d4];
        float q0 = qs[4 * d4], q1 = qs[4 * d4 + 1], q2 = qs[4 * d4 + 2], q3 = qs[4 * d4 + 3];
        s1 += q0 * kv.x + q1 * kv.y + q2 * kv.z + q3 * kv.w;
        s2 += q0 * rv.x + q1 * rv.y + q2 * rv.z + q3 * rv.w;
    }
    float val = s1 * ATTN_SCALE + s2 + ((t > l) ? 1.0f : 0.0f);

    float m = val;
    #pragma unroll
    for (int off = 32; off; off >>= 1) m = fmaxf(m, __shfl_xor(m, off));
    if (lane == 0) swave[wid] = m;
    __syncthreads();
    m = fmaxf(fmaxf(swave[0], swave[1]), fmaxf(swave[2], swave[3]));
    float p = expf(val - m);
    float s = p;
    #pragma unroll
    for (int off = 32; off; off >>= 1) s += __shfl_xor(s, off);
    __syncthreads();
    if (lane == 0) swave[wid] = s;
    __syncthreads();
    float tot = swave[0] + swave[1] + swave[2] + swave[3];
    attn_s[t] = p;
    __syncthreads();

    int d = t & 63, part = t >> 6;
    const float* vbase = qkv + (size_t)(b * SS) * (3 * EE) + 2 * EE + h * HD + d;
    float acc = 0.f;
    int m0 = part * 64;
    #pragma unroll 8
    for (int mm = m0; mm < m0 + 64; mm++)
        acc += attn_s[mm] * vbase[(size_t)mm * (3 * EE)];
    opart[part][d] = acc;
    __syncthreads();
    if (t < 64) {
        float ov = (opart[0][d] + opart[1][d] + opart[2][d] + opart[3][d]) / tot;
        o[(size_t)(b * SS + l) * EE + h * HD + d] = ov;
    }
}

extern "C" void kernel_launch(void* const* d_in, const int* in_sizes, int n_in,
                              void* d_out, int out_size, void* d_ws, size_t ws_size,
                              hipStream_t stream) {
    const int*   src    = (const int*)  d_in[0];
    const float* emb    = (const float*)d_in[1];
    const float* rel    = (const float*)d_in[2];
    const float* nin_s  = (const float*)d_in[3];
    const float* nin_b  = (const float*)d_in[4];
    const float* inW    = (const float*)d_in[5];
    const float* inB    = (const float*)d_in[6];
    const float* outW   = (const float*)d_in[7];
    const float* outB   = (const float*)d_in[8];
    const float* ln1_s  = (const float*)d_in[9];
    const float* ln1_b  = (const float*)d_in[10];
    const float* ln2_s  = (const float*)d_in[11];
    const float* ln2_b  = (const float*)d_in[12];
    const float* w1     = (const float*)d_in[13];
    const float* b1     = (const float*)d_in[14];
    const float* w2     = (const float*)d_in[15];
    const float* b2     = (const float*)d_in[16];
    const float* normf_s= (const float*)d_in[17];
    const float* normf_b= (const float*)d_in[18];
    const float* dec_w  = (const float*)d_in[19];
    const float* dec_b  = (const float*)d_in[20];
    float* out = (float*)d_out;   // [1024, 32000]

    const size_t n_inW  = (size_t)LL * 3 * EE * EE;
    const size_t n_outW = (size_t)LL * EE * EE;
    const size_t n_w1   = (size_t)LL * FFD * EE;
    const size_t n_w2   = (size_t)LL * EE * FFD;
    const size_t n_dec  = (size_t)VV * EE;

    float* x    = (float*)d_ws;                       // [BS,EE] fp32 residual
    bf16*  qkvb = (bf16*)(x + (size_t)BS * EE);       // [BS,3EE] bf16
    bf16*  hb   = qkvb + (size_t)BS * 3 * EE;         // [BS,EE]
    bf16*  ob   = hb + (size_t)BS * EE;               // [BS,EE]
    bf16*  ffb  = ob + (size_t)BS * EE;               // [BS,FFD]
    bf16*  vTb  = ffb + (size_t)BS * FFD;             // [32][64][256]
    bf16*  relb = vTb + (size_t)BS * 512;             // [512][512] (row 511 unused)
    bf16*  inWb  = relb + (size_t)512 * EE;
    bf16*  outWb = inWb + n_inW;
    bf16*  w1b   = outWb + n_outW;
    bf16*  w2b   = w1b + n_w1;
    bf16*  decWb = w2b + n_w2;
    size_t needed = (size_t)((char*)(decWb + n_dec) - (char*)d_ws);

    if (ws_size >= needed) {
        cvt_all<<<29568, 256, 0, stream>>>(inW, outW, w1, w2, dec_w, rel,
                                           inWb, outWb, w1b, w2b, decWb, relb,
                                           src, emb, nin_s, nin_b, x);

        for (int l = 0; l < LL; l++) {
            ln_kernel<bf16><<<BS, 256, 0, stream>>>(x, ln1_s + l * EE, ln1_b + l * EE, hb);
            gemm_bf16<64, 64, 0, 1, 1, 0, 1><<<dim3(BS / 64, 3 * EE / 64), 256, 0, stream>>>(
                hb, inWb + (size_t)l * 3 * EE * EE, inB + (size_t)l * 3 * EE, qkvb, nullptr,
                vTb, BS, 3 * EE, EE);
            attn_mfma<<<BB * HH * 4, 256, 0, stream>>>(qkvb, relb, vTb, ob);
            // out-projection + residual, split-K=2 -> 256 blocks (atomic fp32 combine)
            gemm_bf16<64, 64, 2, 0, 0, 0, 2><<<dim3(BS / 64, EE / 64, 2), 256, 0, stream>>>(
                ob, outWb + (size_t)l * EE * EE, outB + (size_t)l * EE, x, x,
                nullptr, BS, EE, EE);
            ln_kernel<bf16><<<BS, 256, 0, stream>>>(x, ln2_s + l * EE, ln2_b + l * EE, hb);
            gemm_bf16<64, 64, 1, 1, 0, 0, 1><<<dim3(BS / 64, FFD / 64), 256, 0, stream>>>(
                hb, w1b + (size_t)l * FFD * EE, b1 + (size_t)l * FFD, ffb, nullptr,
                nullptr, BS, FFD, EE);
            // FF2 + residual, split-K=4 -> 512 blocks (atomic fp32 combine)
            gemm_bf16<64, 64, 2, 0, 0, 0, 4><<<dim3(BS / 64, EE / 64, 4), 256, 0, stream>>>(
                ffb, w2b + (size_t)l * EE * FFD, b2 + (size_t)l * EE, x, x,
                nullptr, BS, EE, FFD);
        }

        ln_kernel<bf16><<<BS, 256, 0, stream>>>(x, normf_s, normf_b, hb);
        gemm_bf16<128, 128, 0, 0, 0, 1, 1><<<dim3(BS / 128, VV / 128), 256, 0, stream>>>(
            hb, decWb, dec_b, out, nullptr, nullptr, BS, VV, EE);
    } else {
        float* h     = x + (size_t)BS * EE;
        float* qkvf  = h + (size_t)BS * EE;
        float* o     = qkvf + (size_t)BS * 3 * EE;
        float* ffmid = o + (size_t)BS * EE;

        embed_ln_kernel<<<BS, 256, 0, stream>>>(src, emb, nin_s, nin_b, x);
        for (int l = 0; l < LL; l++) {
            ln_kernel<float><<<BS, 256, 0, stream>>>(x, ln1_s + l * EE, ln1_b + l * EE, h);
            gemm_nt<0><<<dim3(3 * EE / 64, BS / 64), 256, 0, stream>>>(
                h, inW + (size_t)l * 3 * EE * EE, inB + (size_t)l * 3 * EE, qkvf, nullptr,
                BS, 3 * EE, EE);
            attn_kernel<<<BB * HH * SS, 256, 0, stream>>>(qkvf, rel, o);
            gemm_nt<2><<<dim3(EE / 64, BS / 64), 256, 0, stream>>>(
                o, outW + (size_t)l * EE * EE, outB + (size_t)l * EE, x, x,
                BS, EE, EE);
            ln_kernel<float><<<BS, 256, 0, stream>>>(x, ln2_s + l * EE, ln2_b + l * EE, h);
            gemm_nt<1><<<dim3(FFD / 64, BS / 64), 256, 0, stream>>>(
                h, w1 + (size_t)l * FFD * EE, b1 + (size_t)l * FFD, ffmid, nullptr,
                BS, FFD, EE);
            gemm_nt<2><<<dim3(EE / 64, BS / 64), 256, 0, stream>>>(
                ffmid, w2 + (size_t)l * EE * FFD, b2 + (size_t)l * EE, x, x,
                BS, EE, FFD);
        }
        ln_kernel<float><<<BS, 256, 0, stream>>>(x, normf_s, normf_b, h);
        gemm_nt<0><<<dim3(VV / 64, BS / 64), 256, 0, stream>>>(
            h, dec_w, dec_b, out, nullptr, BS, VV, EE);
    }
}